// Round 11
// baseline (99.507 us; speedup 1.0000x reference)
//
#include <hip/hip_runtime.h>
#include <math.h>

// MoE conv container, two-phase:
//  prep: x NCHW fp32 -> zero-padded NHWC bf16 (130x130x32) in ws (XCD-swizzled
//        writes matching conv's read affinity), + weights -> MFMA A-layout bf16
//        + BN scale/shift tables.  (~28us ~= BW floor)
//  conv: one 16x32-px region per block = 2 fully-unrolled 8x32 tiles (A panels
//        staged once). 4 waves x [2 rows x 32 cols] per tile. Pixel frags
//        direct from NHWC-padded global (16B/lane, L2/L3-local). Swapped MFMA
//        operands. Latency hiding: tile-0 frag loads before the staging
//        barrier; tile-1 lead rows (fresh names) under tile-0's epilogue.
//        NEW (R11): epilogue bounces each (row, co-half) chunk through a
//        wave-private LDS buffer so each global_store_dwordx4 covers 8 FULL
//        128B lines (8 lanes x 32px x one co), instead of 64 scattered 16B
//        segments across 16 co-planes -- removes store-issue backpressure on
//        the in-order VMEM queue (theory: this was serializing loads vs
//        stores and making pipe times ADD instead of overlap).
//        R8 lesson: keep frag+res liveness low; no regs held across epilogue.
// Fallback to single-kernel (R2) path if ws too small.

#define B_ 64
#define C_ 32
#define H_ 128
#define W_ 128
#define E_ 4
#define K_ 2
#define EPS_ 1e-5f
#define HW_ (H_ * W_)
#define HP_ 130
#define WP_ 130

#define AROW_B 592                          // 288 bf16 = 576B + 16B pad (odd 16B stride)
#define A_LDS_B (C_ * AROW_B)               // 18944 per expert
#define XPAD_BYTES ((size_t)B_ * HP_ * WP_ * C_ * 2)   // 69,222,400
#define AW_OFF   XPAD_BYTES
#define AW_BYTES ((size_t)E_ * A_LDS_B)     // 75,776
#define SCSH_OFF (AW_OFF + AW_BYTES)
#define WS_NEEDED (SCSH_OFF + (size_t)E_ * C_ * 2 * 4)

// conv LDS layout: A panels + scale/shift + per-wave store-transpose buffers
#define LDS_AW   0
#define LDS_SCSH (2 * A_LDS_B)             // 37888
#define LDS_XP   (LDS_SCSH + 512)          // 38400
#define XPBUF_B  2304                      // 16 co x 36 f32 (stride 36 -> 16B-aligned rows)
#define LDS_TOT  (LDS_XP + 4 * XPBUF_B)    // 47616 -> still 3 blocks/CU

typedef __attribute__((ext_vector_type(4))) float  f32x4;
typedef __attribute__((ext_vector_type(8))) short  bf16x8;
typedef __attribute__((ext_vector_type(8))) unsigned short u16x8;
typedef __attribute__((ext_vector_type(4))) unsigned short u16x4;

__device__ inline unsigned short f2bf(float f) {  // round-to-nearest-even
  unsigned u = __builtin_bit_cast(unsigned, f);
  return (unsigned short)((u + 0x7fffu + ((u >> 16) & 1u)) >> 16);
}

__device__ inline float fast_sigmoid(float y) {   // hw rcp: 1 op vs ~9-op div
  return __builtin_amdgcn_rcpf(1.f + __expf(-y));
}

__device__ inline void gload16(const void* g, const void* l) {
  __builtin_amdgcn_global_load_lds(
      (const __attribute__((address_space(1))) unsigned int*)g,
      (__attribute__((address_space(3))) unsigned int*)l, 16, 0, 0);
}

// ---------------- phase A: transpose/convert + weight prep ----------------
__global__ __launch_bounds__(256, 4)
void prep_kernel(const float* __restrict__ x,
                 const float* __restrict__ Wc,
                 const float* __restrict__ gamma,
                 const float* __restrict__ beta,
                 const float* __restrict__ mean,
                 const float* __restrict__ var,
                 unsigned short* __restrict__ wsu) {
  const int bid = blockIdx.x;
  const int tid = threadIdx.x;

  if (bid >= B_ * HP_) {
    // ---- weight block: expert e -> A[e][co][o*32+ci] bf16, stride 592B ----
    int e = bid - B_ * HP_;
    unsigned short* aw = (unsigned short*)((char*)wsu + AW_OFF) + (size_t)e * (A_LDS_B / 2);
    int co  = tid >> 3;
    int ci4 = (tid & 7) * 4;
    const float* wp = Wc + (((size_t)e * C_ + co) * C_ + ci4) * 9;
    float wv[36];
#pragma unroll
    for (int j = 0; j < 36; ++j) wv[j] = wp[j];
    unsigned short* arow = aw + co * (AROW_B / 2) + ci4;
#pragma unroll
    for (int o = 0; o < 9; ++o) {
      u16x4 pk;
#pragma unroll
      for (int q = 0; q < 4; ++q) pk[q] = f2bf(wv[q * 9 + o]);
      *(u16x4*)(arow + o * C_) = pk;
    }
    if (tid < C_) {
      float g  = gamma[e * C_ + tid];
      float bt = beta[e * C_ + tid];
      float mn = mean[e * C_ + tid];
      float vr = var[e * C_ + tid];
      float sc = g * rsqrtf(vr + EPS_);
      float* scsh = (float*)((char*)wsu + SCSH_OFF);
      scsh[(e * C_ + tid) * 2 + 0] = sc;
      scsh[(e * C_ + tid) * 2 + 1] = bt - mn * sc;
    }
    return;
  }

  // XCD-aligned bijection: sample b handled by blocks with bid%8 == b%8,
  // matching conv_kernel's read affinity (per-XCD L2 locality).
  const int xg = bid >> 3;                  // 0..1039
  const int u  = bid & 7;
  const int b  = (xg / HP_) * 8 + u;        // 0..63
  const int hp = xg % HP_;                  // 0..129
  unsigned short* xrow = wsu + ((size_t)b * HP_ + hp) * WP_ * C_;

  if (hp == 0 || hp == HP_ - 1) {           // zero pad rows
    u16x8 z = (u16x8)0;
    for (int c = tid; c < WP_ * C_ / 8; c += 256) *(u16x8*)(xrow + c * 8) = z;
    return;
  }

  __shared__ float tile[C_ * W_];           // 16 KB
  const int h = hp - 1;
#pragma unroll
  for (int p = 0; p < 4; ++p) {
    int n  = p * 1024 + tid * 4;
    int c  = n >> 7;
    int px = n & 127;
    *(f32x4*)(tile + n) =
        *(const f32x4*)(x + (((size_t)b * C_ + c) * H_ + h) * W_ + px);
  }
  __syncthreads();

  const int px = tid >> 1;
  const int c0 = (tid & 1) * 16;
  u16x8 o0, o1;
#pragma unroll
  for (int j = 0; j < 8; ++j) o0[j] = f2bf(tile[(c0 + j) * W_ + px]);
#pragma unroll
  for (int j = 0; j < 8; ++j) o1[j] = f2bf(tile[(c0 + 8 + j) * W_ + px]);
  unsigned short* dst = xrow + (px + 1) * C_ + c0;
  *(u16x8*)dst = o0;
  *(u16x8*)(dst + 8) = o1;

  if (tid < 4) {                            // zero pad cols 0 and 129
    int pxb = (tid >> 1) ? (WP_ - 1) : 0;
    int hf  = tid & 1;
    u16x8 z = (u16x8)0;
    unsigned short* d2 = xrow + pxb * C_ + hf * 16;
    *(u16x8*)d2 = z;
    *(u16x8*)(d2 + 8) = z;
  }
}

// ---------------- phase B: conv via MFMA (swapped operands) ----------------
__global__ __launch_bounds__(256, 3)
void conv_kernel(const unsigned short* __restrict__ xpad,
                 const unsigned short* __restrict__ aw_all,
                 const float* __restrict__ scsh_all,
                 const float* __restrict__ weights,
                 const int* __restrict__ indices,
                 float* __restrict__ out) {
  __shared__ __align__(16) unsigned char lds[LDS_TOT];
  const int tid  = threadIdx.x;
  const int lane = tid & 63;
  const int wid  = tid >> 6;

  // XCD swizzle: all 32 blocks of a sample land on one XCD (bid%8 assumption).
  const int bid  = blockIdx.x;              // grid 2048
  const int xcd  = bid & 7;
  const int ii   = bid >> 3;                // 0..255
  const int b    = (ii >> 5) * 8 + xcd;     // bijective over (b, region)
  const int reg_ = ii & 31;
  const int rowg = reg_ >> 2;               // 0..7 -> 16-row band
  const int cseg = reg_ & 3;                // 0..3 -> 32-col segment
  const int c0   = cseg * 32;

  const int   e0  = indices[b * K_ + 0];
  const int   e1  = indices[b * K_ + 1];
  const float wk0 = weights[b * K_ + 0];
  const float wk1 = weights[b * K_ + 1];
  const bool  dup = (e0 == e1);
  const float wka = dup ? (wk0 + wk1) : wk0;

  // ---- stage A panels (1 or 2 experts) via global_load_lds ----
  {
    const int nA = (dup ? 1 : 2) * 1184;    // 16B chunks
    for (int base = wid * 64; base < nA; base += 256) {
      int c = base + lane;
      int e = (c < 1184) ? e0 : e1;
      int r = (c < 1184) ? c : c - 1184;
      const unsigned short* src = aw_all + (size_t)e * (A_LDS_B / 2) + r * 8;
      if (c < nA) gload16(src, lds + LDS_AW + base * 16);
    }
  }
  // ---- stage BN scale/shift ----
  if (tid < 2 * C_) {
    int s  = tid >> 5;
    int co = tid & 31;
    int e  = s ? e1 : e0;
    float* d = (float*)(lds + LDS_SCSH) + (s * C_ + co) * 2;
    d[0] = scsh_all[(e * C_ + co) * 2 + 0];
    d[1] = scsh_all[(e * C_ + co) * 2 + 1];
  }

  const int lx = lane & 15;                 // px within M-tile / co within N-tile
  const int sl = lane >> 4;                 // k-slot (8 ci)

  // Wave-private store-transpose buffer: [16 co][36 f32] (stride 36 -> 16B rows)
  float* xbuf = (float*)(lds + LDS_XP + wid * XPBUF_B);

  // Column-base pointer for this wave's 32-col segment (row added per tile).
  const unsigned short* cbase =
      xpad + ((size_t)b * HP_ * WP_ + c0 + lx) * C_ + sl * 8;

  // window s = m2*3+dx -> col offset (s/3)*16 + (s%3); row hr in padded coords.
#define LOADROW(dst, rbase, hr)                                               \
  {                                                                           \
    const unsigned short* _p = cbase + ((size_t)((rbase) + (hr)) * WP_) * C_; \
    _Pragma("unroll")                                                         \
    for (int s_ = 0; s_ < 6; ++s_)                                            \
      dst[s_] = *(const bf16x8*)(_p + ((s_ / 3) * 16 + (s_ % 3)) * C_);       \
  }

  // 9-tap MFMA main loop over rolling rows A0/B0 (consumed; end: rows 2,3).
#define MAINLOOP(R0, A0, B0)                                                  \
  _Pragma("unroll")                                                           \
  for (int dy = 0; dy < 3; ++dy) {                                            \
    bf16x8 FC[6];                                                             \
    if (dy < 2) LOADROW(FC, R0, dy + 2)                                       \
    _Pragma("unroll")                                                         \
    for (int dx = 0; dx < 3; ++dx) {                                          \
      const int o = dy * 3 + dx;                                              \
      bf16x8 bf0[2], bf1[2];                                                  \
      _Pragma("unroll")                                                       \
      for (int nc = 0; nc < 2; ++nc)                                          \
        bf0[nc] = *(const bf16x8*)(lds + LDS_AW + (nc * 16 + lx) * AROW_B + o * 64 + sl * 16); \
      if (!dup) {                                                             \
        _Pragma("unroll")                                                     \
        for (int nc = 0; nc < 2; ++nc)                                        \
          bf1[nc] = *(const bf16x8*)(lds + LDS_AW + A_LDS_B + (nc * 16 + lx) * AROW_B + o * 64 + sl * 16); \
      }                                                                       \
      __builtin_amdgcn_s_setprio(1);                                          \
      _Pragma("unroll")                                                       \
      for (int j = 0; j < 2; ++j)                                             \
        _Pragma("unroll")                                                     \
        for (int m2 = 0; m2 < 2; ++m2) {                                      \
          bf16x8 Af = j ? B0[m2 * 3 + dx] : A0[m2 * 3 + dx];                  \
          _Pragma("unroll")                                                   \
          for (int nc = 0; nc < 2; ++nc)                                      \
            acc[0][j * 2 + m2][nc] =                                          \
                __builtin_amdgcn_mfma_f32_16x16x32_bf16(Af, bf0[nc], acc[0][j * 2 + m2][nc], 0, 0, 0); \
          if (!dup) {                                                         \
            _Pragma("unroll")                                                 \
            for (int nc = 0; nc < 2; ++nc)                                    \
              acc[1][j * 2 + m2][nc] =                                        \
                  __builtin_amdgcn_mfma_f32_16x16x32_bf16(Af, bf1[nc], acc[1][j * 2 + m2][nc], 0, 0, 0); \
          }                                                                   \
        }                                                                     \
      __builtin_amdgcn_s_setprio(0);                                          \
    }                                                                         \
    _Pragma("unroll")                                                         \
    for (int s_ = 0; s_ < 6; ++s_) { A0[s_] = B0[s_]; B0[s_] = FC[s_]; }      \
  }

  // Epilogue with LDS store-transpose: per (j,nc) chunk, scatter both m2
  // quads into xbuf ([co][px]), then re-read so 8 consecutive lanes cover 32
  // contiguous px of one co -> global_store_dwordx4 = 8 full 128B lines.
  // Wave-private buffer, no barrier; in-wave lgkmcnt orders write->read.
#define EPILOGUE(R0)                                                          \
  _Pragma("unroll")                                                           \
  for (int j = 0; j < 2; ++j)                                                 \
    _Pragma("unroll")                                                         \
    for (int nc = 0; nc < 2; ++nc) {                                          \
      _Pragma("unroll")                                                       \
      for (int m2 = 0; m2 < 2; ++m2) {                                        \
        const int mt = j * 2 + m2;                                            \
        const int co = nc * 16 + lx;                                          \
        f32x4 rv = (f32x4){0.f, 0.f, 0.f, 0.f};                               \
        _Pragma("unroll")                                                     \
        for (int s = 0; s < 2; ++s) {                                         \
          if (s == 1 && dup) break;                                           \
          float wk = s ? wk1 : wka;                                           \
          float sc = scshl[(s * C_ + co) * 2 + 0];                            \
          float sh = scshl[(s * C_ + co) * 2 + 1];                            \
          _Pragma("unroll")                                                   \
          for (int r = 0; r < 4; ++r) {                                       \
            float y = acc[s][mt][nc][r] * sc + sh;                            \
            rv[r] += wk * y * fast_sigmoid(y);                                \
          }                                                                   \
        }                                                                     \
        *(f32x4*)&xbuf[lx * 36 + m2 * 16 + sl * 4] = rv;                      \
      }                                                                       \
      _Pragma("unroll")                                                       \
      for (int k = 0; k < 2; ++k) {                                           \
        const int co16 = k * 8 + (lane >> 3);                                 \
        const int px   = (lane & 7) * 4;                                      \
        f32x4 v = *(const f32x4*)&xbuf[co16 * 36 + px];                       \
        float* ob = out + ((size_t)b * C_ + nc * 16 + co16) * HW_ +           \
                    (size_t)((R0) + j) * W_ + c0 + px;                        \
        *(f32x4*)ob = v;                                                      \
      }                                                                       \
    }

  // ---- pre-barrier: issue tile-0's first two halo rows (overlap DMA drain)
  bf16x8 FA[6], FB[6];
  const int r0t0 = rowg * 16 + wid * 2;     // tile-0 first image row
  const int r0t1 = r0t0 + 8;                // tile-1 first image row
  LOADROW(FA, r0t0, 0)
  LOADROW(FB, r0t0, 1)

  __syncthreads();                          // drains gload_lds + frag loads

  const float* scshl = (const float*)(lds + LDS_SCSH);

  f32x4 acc[2][4][2];                       // [exp][mt=j*2+m2][nc]
#pragma unroll
  for (int s = 0; s < 2; ++s)
#pragma unroll
    for (int mt = 0; mt < 4; ++mt)
#pragma unroll
      for (int nc = 0; nc < 2; ++nc) acc[s][mt][nc] = (f32x4){0.f, 0.f, 0.f, 0.f};

  // ================= tile 0 =================
  MAINLOOP(r0t0, FA, FB)

  // prefetch tile-1 lead rows into fresh names; hidden under the epilogue
  bf16x8 NA[6], NB[6];
  LOADROW(NA, r0t1, 0)
  LOADROW(NB, r0t1, 1)

  EPILOGUE(r0t0)

  // ================= tile 1 =================
#pragma unroll
  for (int s = 0; s < 2; ++s)
#pragma unroll
    for (int mt = 0; mt < 4; ++mt)
#pragma unroll
      for (int nc = 0; nc < 2; ++nc) acc[s][mt][nc] = (f32x4){0.f, 0.f, 0.f, 0.f};

  MAINLOOP(r0t1, NA, NB)
  EPILOGUE(r0t1)

#undef LOADROW
#undef MAINLOOP
#undef EPILOGUE
}

// ---------------- fallback (R2 single kernel) if ws too small ----------------
#define FHALO 18
#define FNPX (FHALO * FHALO)
#define FPX_B 64
#define FIN_LDS_B (FNPX * FPX_B)
#define FSC_OFF (FIN_LDS_B + 2 * A_LDS_B)
#define FLDS_TOTAL (FSC_OFF + 2 * C_ * 8)
#define TH 16
#define TW 16

__global__ __launch_bounds__(256, 2)
void moe_fallback_kernel(const float* __restrict__ x,
                         const float* __restrict__ weights,
                         const int* __restrict__ indices,
                         const float* __restrict__ Wc,
                         const float* __restrict__ gamma,
                         const float* __restrict__ beta,
                         const float* __restrict__ mean,
                         const float* __restrict__ var,
                         float* __restrict__ out) {
  __shared__ __align__(16) unsigned char lds[FLDS_TOTAL];
  unsigned char* in_t = lds;
  unsigned char* aw0  = lds + FIN_LDS_B;
  unsigned char* aw1  = lds + FIN_LDS_B + A_LDS_B;
  float*         scsh = (float*)(lds + FSC_OFF);

  const int tid = threadIdx.x;
  const int tiles_per_row = W_ / TW;
  const int tiles_per_img = (H_ / TH) * tiles_per_row;
  const int b    = blockIdx.x / tiles_per_img;
  const int tile = blockIdx.x % tiles_per_img;
  const int th0  = (tile / tiles_per_row) * TH;
  const int tw0  = (tile % tiles_per_row) * TW;

  const int   e0  = indices[b * K_ + 0];
  const int   e1  = indices[b * K_ + 1];
  const float wk0 = weights[b * K_ + 0];
  const float wk1 = weights[b * K_ + 1];
  const bool  dup = (e0 == e1);
  const float wka = dup ? (wk0 + wk1) : wk0;

  const float* xb = x + (size_t)b * C_ * HW_;
  for (int i = tid; i < FNPX * 4; i += 256) {
    int px = i % FNPX;
    int cb = i / FNPX;
    int hy = px / FHALO, hx = px % FHALO;
    int gh = th0 + hy - 1, gw = tw0 + hx - 1;
    u16x8 pk = (u16x8)0;
    if (gh >= 0 && gh < H_ && gw >= 0 && gw < W_) {
      const float* src = xb + (size_t)(cb * 8) * HW_ + (size_t)gh * W_ + gw;
#pragma unroll
      for (int j = 0; j < 8; ++j) pk[j] = f2bf(src[(size_t)j * HW_]);
    }
    int slot = cb ^ (px & 3);
    *(u16x8*)(in_t + px * FPX_B + slot * 16) = pk;
  }
  {
    int co  = tid >> 3;
    int ci4 = (tid & 7) * 4;
#pragma unroll
    for (int s = 0; s < 2; ++s) {
      int e = s ? e1 : e0;
      const float* wp = Wc + (size_t)e * C_ * C_ * 9 + (size_t)co * C_ * 9 + (size_t)ci4 * 9;
      float wv[36];
#pragma unroll
      for (int j = 0; j < 36; ++j) wv[j] = wp[j];
      unsigned char* arow = (s ? aw1 : aw0) + co * AROW_B + ci4 * 2;
#pragma unroll
      for (int o = 0; o < 9; ++o) {
        u16x4 pk;
#pragma unroll
        for (int q = 0; q < 4; ++q) pk[q] = f2bf(wv[q * 9 + o]);
        *(u16x4*)(arow + o * 64) = pk;
      }
    }
  }
  if (tid < 64) {
    int s  = tid >> 5;
    int co = tid & 31;
    int e  = s ? e1 : e0;
    float g  = gamma[e * C_ + co];
    float bt = beta[e * C_ + co];
    float mn = mean[e * C_ + co];
    float vr = var[e * C_ + co];
    float sc = g * rsqrtf(vr + EPS_);
    scsh[(s * C_ + co) * 2 + 0] = sc;
    scsh[(s * C_ + co) * 2 + 1] = bt - mn * sc;
  }
  __syncthreads();

  const int lane = tid & 63;
  const int w    = tid >> 6;
  const int lx   = lane & 15;
  const int sl   = lane >> 4;

  f32x4 acc[2][2][4];
#pragma unroll
  for (int s = 0; s < 2; ++s)
#pragma unroll
    for (int m = 0; m < 2; ++m)
#pragma unroll
      for (int j = 0; j < 4; ++j) acc[s][m][j] = (f32x4){0.f, 0.f, 0.f, 0.f};

  int dy = 0, dx = 0;
#pragma unroll 1
  for (int o = 0; o < 9; ++o) {
    bf16x8 bf[4];
#pragma unroll
    for (int j = 0; j < 4; ++j) {
      int hp   = (4 * w + j + dy) * FHALO + (lx + dx);
      int slot = sl ^ (hp & 3);
      bf[j] = *(const bf16x8*)(in_t + hp * FPX_B + slot * 16);
    }
    bf16x8 af0[2], af1[2];
#pragma unroll
    for (int m = 0; m < 2; ++m) {
      int ro = (m * 16 + lx) * AROW_B + o * 64 + sl * 16;
      af0[m] = *(const bf16x8*)(aw0 + ro);
      af1[m] = *(const bf16x8*)(aw1 + ro);
    }
#pragma unroll
    for (int m = 0; m < 2; ++m)
#pragma unroll
      for (int j = 0; j < 4; ++j)
        acc[0][m][j] = __builtin_amdgcn_mfma_f32_16x16x32_bf16(af0[m], bf[j], acc[0][m][j], 0, 0, 0);
    if (!dup) {
#pragma unroll
      for (int m = 0; m < 2; ++m)
#pragma unroll
        for (int j = 0; j < 4; ++j)
          acc[1][m][j] = __builtin_amdgcn_mfma_f32_16x16x32_bf16(af1[m], bf[j], acc[1][m][j], 0, 0, 0);
    }
    if (++dx == 3) { dx = 0; ++dy; }
  }

  float res[2][4][4];
#pragma unroll
  for (int m = 0; m < 2; ++m)
#pragma unroll
    for (int j = 0; j < 4; ++j)
#pragma unroll
      for (int r = 0; r < 4; ++r) res[m][j][r] = 0.f;

#pragma unroll
  for (int s = 0; s < 2; ++s) {
    if (s == 1 && dup) break;
    float wk = s ? wk1 : wka;
#pragma unroll
    for (int m = 0; m < 2; ++m)
#pragma unroll
      for (int r = 0; r < 4; ++r) {
        int co = m * 16 + sl * 4 + r;
        float sc = scsh[(s * C_ + co) * 2 + 0];
        float sh = scsh[(s * C_ + co) * 2 + 1];
#pragma unroll
        for (int j = 0; j < 4; ++j) {
          float y = acc[s][m][j][r] * sc + sh;
          res[m][j][r] += wk * y * fast_sigmoid(y);
        }
      }
  }
#pragma unroll
  for (int m = 0; m < 2; ++m)
#pragma unroll
    for (int r = 0; r < 4; ++r) {
      int co = m * 16 + sl * 4 + r;
      float* ob = out + ((size_t)b * C_ + co) * HW_ + (size_t)th0 * W_ + tw0 + lx;
#pragma unroll
      for (int j = 0; j < 4; ++j)
        ob[(size_t)(4 * w + j) * W_] = res[m][j][r];
    }
}

extern "C" void kernel_launch(void* const* d_in, const int* in_sizes, int n_in,
                              void* d_out, int out_size, void* d_ws, size_t ws_size,
                              hipStream_t stream) {
  const float* x       = (const float*)d_in[0];
  const float* weights = (const float*)d_in[1];
  const int*   indices = (const int*)d_in[2];
  const float* Wc      = (const float*)d_in[3];
  const float* gamma   = (const float*)d_in[4];
  const float* beta    = (const float*)d_in[5];
  const float* mean    = (const float*)d_in[6];
  const float* var     = (const float*)d_in[7];
  float* out = (float*)d_out;

  if (d_ws != nullptr && ws_size >= WS_NEEDED) {
    unsigned short* wsu = (unsigned short*)d_ws;
    const unsigned short* aw_all   = (const unsigned short*)((char*)d_ws + AW_OFF);
    const float*          scsh_all = (const float*)((char*)d_ws + SCSH_OFF);
    prep_kernel<<<B_ * HP_ + E_, 256, 0, stream>>>(x, Wc, gamma, beta, mean, var, wsu);
    conv_kernel<<<2048, 256, 0, stream>>>(wsu, aw_all, scsh_all, weights, indices, out);
  } else {
    moe_fallback_kernel<<<B_ * 64, 256, 0, stream>>>(
        x, weights, indices, Wc, gamma, beta, mean, var, out);
  }
}

// Round 12
// 95.816 us; speedup vs baseline: 1.0385x; 1.0385x over previous
//
#include <hip/hip_runtime.h>
#include <math.h>

// MoE conv container, two-phase:
//  prep: x NCHW fp32 -> zero-padded NHWC bf16 (130x130x32) in ws (XCD-swizzled
//        writes matching conv's read affinity), + weights -> MFMA A-layout bf16
//        + BN scale/shift tables.  (~28us ~= BW floor)
//  conv: one 16x32-px region per block = 2 fully-unrolled 8x32 tiles (A panels
//        staged once). 4 waves x [2 rows x 32 cols] per tile. Pixel frags
//        direct from NHWC-padded global (16B/lane, L2/L3-local). Swapped MFMA
//        operands -> dwordx4 stores filling full 128B lines. Latency hiding:
//        tile-0 frag loads before the staging barrier; tile-1 lead rows
//        (fresh names) under tile-0's epilogue; streamed per-quad stores.
//        R12: BN scale/shift cached in 8 regs/lane from the L2-hot global
//        table (drops ~110 LDS reads + addr math per wave per block).
//        R11 lesson: LDS store-transpose of the epilogue = -10us (store
//        scatter was NOT a bottleneck; stores already merge in L2).
//        R8 lesson: never hold frag regs live across the epilogue (spill).
// Fallback to single-kernel (R2) path if ws too small.

#define B_ 64
#define C_ 32
#define H_ 128
#define W_ 128
#define E_ 4
#define K_ 2
#define EPS_ 1e-5f
#define HW_ (H_ * W_)
#define HP_ 130
#define WP_ 130

#define AROW_B 592                          // 288 bf16 = 576B + 16B pad (odd 16B stride)
#define A_LDS_B (C_ * AROW_B)               // 18944 per expert
#define XPAD_BYTES ((size_t)B_ * HP_ * WP_ * C_ * 2)   // 69,222,400
#define AW_OFF   XPAD_BYTES
#define AW_BYTES ((size_t)E_ * A_LDS_B)     // 75,776
#define SCSH_OFF (AW_OFF + AW_BYTES)
#define WS_NEEDED (SCSH_OFF + (size_t)E_ * C_ * 2 * 4)

// conv LDS layout: A panels only
#define LDS_AW   0
#define LDS_TOT  (2 * A_LDS_B)             // 37888 -> 3 blocks/CU (VGPR-capped)

typedef __attribute__((ext_vector_type(4))) float  f32x4;
typedef __attribute__((ext_vector_type(2))) float  f32x2;
typedef __attribute__((ext_vector_type(8))) short  bf16x8;
typedef __attribute__((ext_vector_type(8))) unsigned short u16x8;
typedef __attribute__((ext_vector_type(4))) unsigned short u16x4;

__device__ inline unsigned short f2bf(float f) {  // round-to-nearest-even
  unsigned u = __builtin_bit_cast(unsigned, f);
  return (unsigned short)((u + 0x7fffu + ((u >> 16) & 1u)) >> 16);
}

__device__ inline float fast_sigmoid(float y) {   // hw rcp: 1 op vs ~9-op div
  return __builtin_amdgcn_rcpf(1.f + __expf(-y));
}

__device__ inline void gload16(const void* g, const void* l) {
  __builtin_amdgcn_global_load_lds(
      (const __attribute__((address_space(1))) unsigned int*)g,
      (__attribute__((address_space(3))) unsigned int*)l, 16, 0, 0);
}

// ---------------- phase A: transpose/convert + weight prep ----------------
__global__ __launch_bounds__(256, 4)
void prep_kernel(const float* __restrict__ x,
                 const float* __restrict__ Wc,
                 const float* __restrict__ gamma,
                 const float* __restrict__ beta,
                 const float* __restrict__ mean,
                 const float* __restrict__ var,
                 unsigned short* __restrict__ wsu) {
  const int bid = blockIdx.x;
  const int tid = threadIdx.x;

  if (bid >= B_ * HP_) {
    // ---- weight block: expert e -> A[e][co][o*32+ci] bf16, stride 592B ----
    int e = bid - B_ * HP_;
    unsigned short* aw = (unsigned short*)((char*)wsu + AW_OFF) + (size_t)e * (A_LDS_B / 2);
    int co  = tid >> 3;
    int ci4 = (tid & 7) * 4;
    const float* wp = Wc + (((size_t)e * C_ + co) * C_ + ci4) * 9;
    float wv[36];
#pragma unroll
    for (int j = 0; j < 36; ++j) wv[j] = wp[j];
    unsigned short* arow = aw + co * (AROW_B / 2) + ci4;
#pragma unroll
    for (int o = 0; o < 9; ++o) {
      u16x4 pk;
#pragma unroll
      for (int q = 0; q < 4; ++q) pk[q] = f2bf(wv[q * 9 + o]);
      *(u16x4*)(arow + o * C_) = pk;
    }
    if (tid < C_) {
      float g  = gamma[e * C_ + tid];
      float bt = beta[e * C_ + tid];
      float mn = mean[e * C_ + tid];
      float vr = var[e * C_ + tid];
      float sc = g * rsqrtf(vr + EPS_);
      float* scsh = (float*)((char*)wsu + SCSH_OFF);
      scsh[(e * C_ + tid) * 2 + 0] = sc;
      scsh[(e * C_ + tid) * 2 + 1] = bt - mn * sc;
    }
    return;
  }

  // XCD-aligned bijection: sample b handled by blocks with bid%8 == b%8,
  // matching conv_kernel's read affinity (per-XCD L2 locality).
  const int xg = bid >> 3;                  // 0..1039
  const int u  = bid & 7;
  const int b  = (xg / HP_) * 8 + u;        // 0..63
  const int hp = xg % HP_;                  // 0..129
  unsigned short* xrow = wsu + ((size_t)b * HP_ + hp) * WP_ * C_;

  if (hp == 0 || hp == HP_ - 1) {           // zero pad rows
    u16x8 z = (u16x8)0;
    for (int c = tid; c < WP_ * C_ / 8; c += 256) *(u16x8*)(xrow + c * 8) = z;
    return;
  }

  __shared__ float tile[C_ * W_];           // 16 KB
  const int h = hp - 1;
#pragma unroll
  for (int p = 0; p < 4; ++p) {
    int n  = p * 1024 + tid * 4;
    int c  = n >> 7;
    int px = n & 127;
    *(f32x4*)(tile + n) =
        *(const f32x4*)(x + (((size_t)b * C_ + c) * H_ + h) * W_ + px);
  }
  __syncthreads();

  const int px = tid >> 1;
  const int c0 = (tid & 1) * 16;
  u16x8 o0, o1;
#pragma unroll
  for (int j = 0; j < 8; ++j) o0[j] = f2bf(tile[(c0 + j) * W_ + px]);
#pragma unroll
  for (int j = 0; j < 8; ++j) o1[j] = f2bf(tile[(c0 + 8 + j) * W_ + px]);
  unsigned short* dst = xrow + (px + 1) * C_ + c0;
  *(u16x8*)dst = o0;
  *(u16x8*)(dst + 8) = o1;

  if (tid < 4) {                            // zero pad cols 0 and 129
    int pxb = (tid >> 1) ? (WP_ - 1) : 0;
    int hf  = tid & 1;
    u16x8 z = (u16x8)0;
    unsigned short* d2 = xrow + pxb * C_ + hf * 16;
    *(u16x8*)d2 = z;
    *(u16x8*)(d2 + 8) = z;
  }
}

// ---------------- phase B: conv via MFMA (swapped operands) ----------------
__global__ __launch_bounds__(256, 3)
void conv_kernel(const unsigned short* __restrict__ xpad,
                 const unsigned short* __restrict__ aw_all,
                 const float* __restrict__ scsh_all,
                 const float* __restrict__ weights,
                 const int* __restrict__ indices,
                 float* __restrict__ out) {
  __shared__ __align__(16) unsigned char lds[LDS_TOT];
  const int tid  = threadIdx.x;
  const int lane = tid & 63;
  const int wid  = tid >> 6;

  // XCD swizzle: all 32 blocks of a sample land on one XCD (bid%8 assumption).
  const int bid  = blockIdx.x;              // grid 2048
  const int xcd  = bid & 7;
  const int ii   = bid >> 3;                // 0..255
  const int b    = (ii >> 5) * 8 + xcd;     // bijective over (b, region)
  const int reg_ = ii & 31;
  const int rowg = reg_ >> 2;               // 0..7 -> 16-row band
  const int cseg = reg_ & 3;                // 0..3 -> 32-col segment
  const int c0   = cseg * 32;

  const int   e0  = indices[b * K_ + 0];
  const int   e1  = indices[b * K_ + 1];
  const float wk0 = weights[b * K_ + 0];
  const float wk1 = weights[b * K_ + 1];
  const bool  dup = (e0 == e1);
  const float wka = dup ? (wk0 + wk1) : wk0;

  // ---- stage A panels (1 or 2 experts) via global_load_lds ----
  {
    const int nA = (dup ? 1 : 2) * 1184;    // 16B chunks
    for (int base = wid * 64; base < nA; base += 256) {
      int c = base + lane;
      int e = (c < 1184) ? e0 : e1;
      int r = (c < 1184) ? c : c - 1184;
      const unsigned short* src = aw_all + (size_t)e * (A_LDS_B / 2) + r * 8;
      if (c < nA) gload16(src, lds + LDS_AW + base * 16);
    }
  }

  const int lx = lane & 15;                 // px within M-tile / co within N-tile
  const int sl = lane >> 4;                 // k-slot (8 ci)

  // ---- BN scale/shift cached in registers (L2-hot 1KB table, 4x8B loads) ----
  float scr[2][2], shr[2][2];               // [slot][nc]
#pragma unroll
  for (int s = 0; s < 2; ++s) {
    int e = s ? e1 : e0;
#pragma unroll
    for (int nc = 0; nc < 2; ++nc) {
      int co = nc * 16 + lx;
      f32x2 p = *(const f32x2*)&scsh_all[(e * C_ + co) * 2];
      scr[s][nc] = p[0];
      shr[s][nc] = p[1];
    }
  }

  // Column-base pointer for this wave's 32-col segment (row added per tile).
  const unsigned short* cbase =
      xpad + ((size_t)b * HP_ * WP_ + c0 + lx) * C_ + sl * 8;

  // window s = m2*3+dx -> col offset (s/3)*16 + (s%3); row hr in padded coords.
#define LOADROW(dst, rbase, hr)                                               \
  {                                                                           \
    const unsigned short* _p = cbase + ((size_t)((rbase) + (hr)) * WP_) * C_; \
    _Pragma("unroll")                                                         \
    for (int s_ = 0; s_ < 6; ++s_)                                            \
      dst[s_] = *(const bf16x8*)(_p + ((s_ / 3) * 16 + (s_ % 3)) * C_);       \
  }

  // 9-tap MFMA main loop over rolling rows A0/B0 (consumed; end: rows 2,3).
#define MAINLOOP(R0, A0, B0)                                                  \
  _Pragma("unroll")                                                           \
  for (int dy = 0; dy < 3; ++dy) {                                            \
    bf16x8 FC[6];                                                             \
    if (dy < 2) LOADROW(FC, R0, dy + 2)                                       \
    _Pragma("unroll")                                                         \
    for (int dx = 0; dx < 3; ++dx) {                                          \
      const int o = dy * 3 + dx;                                              \
      bf16x8 bf0[2], bf1[2];                                                  \
      _Pragma("unroll")                                                       \
      for (int nc = 0; nc < 2; ++nc)                                          \
        bf0[nc] = *(const bf16x8*)(lds + LDS_AW + (nc * 16 + lx) * AROW_B + o * 64 + sl * 16); \
      if (!dup) {                                                             \
        _Pragma("unroll")                                                     \
        for (int nc = 0; nc < 2; ++nc)                                        \
          bf1[nc] = *(const bf16x8*)(lds + LDS_AW + A_LDS_B + (nc * 16 + lx) * AROW_B + o * 64 + sl * 16); \
      }                                                                       \
      __builtin_amdgcn_s_setprio(1);                                          \
      _Pragma("unroll")                                                       \
      for (int j = 0; j < 2; ++j)                                             \
        _Pragma("unroll")                                                     \
        for (int m2 = 0; m2 < 2; ++m2) {                                      \
          bf16x8 Af = j ? B0[m2 * 3 + dx] : A0[m2 * 3 + dx];                  \
          _Pragma("unroll")                                                   \
          for (int nc = 0; nc < 2; ++nc)                                      \
            acc[0][j * 2 + m2][nc] =                                          \
                __builtin_amdgcn_mfma_f32_16x16x32_bf16(Af, bf0[nc], acc[0][j * 2 + m2][nc], 0, 0, 0); \
          if (!dup) {                                                         \
            _Pragma("unroll")                                                 \
            for (int nc = 0; nc < 2; ++nc)                                    \
              acc[1][j * 2 + m2][nc] =                                        \
                  __builtin_amdgcn_mfma_f32_16x16x32_bf16(Af, bf1[nc], acc[1][j * 2 + m2][nc], 0, 0, 0); \
          }                                                                   \
        }                                                                     \
      __builtin_amdgcn_s_setprio(0);                                          \
    }                                                                         \
    _Pragma("unroll")                                                         \
    for (int s_ = 0; s_ < 6; ++s_) { A0[s_] = B0[s_]; B0[s_] = FC[s_]; }      \
  }

  // Streamed epilogue: compute one f32x4 quad (both experts) and store it
  // immediately -> res liveness is 4 regs, not 32. BN params from registers.
#define EPILOGUE(R0)                                                          \
  _Pragma("unroll")                                                           \
  for (int j = 0; j < 2; ++j)                                                 \
    _Pragma("unroll")                                                         \
    for (int m2 = 0; m2 < 2; ++m2)                                            \
      _Pragma("unroll")                                                       \
      for (int nc = 0; nc < 2; ++nc) {                                        \
        const int mt = j * 2 + m2;                                            \
        const int co = nc * 16 + lx;                                          \
        f32x4 rv = (f32x4){0.f, 0.f, 0.f, 0.f};                               \
        _Pragma("unroll")                                                     \
        for (int s = 0; s < 2; ++s) {                                         \
          if (s == 1 && dup) break;                                           \
          float wk = s ? wk1 : wka;                                           \
          float sc = scr[s][nc];                                              \
          float sh = shr[s][nc];                                              \
          _Pragma("unroll")                                                   \
          for (int r = 0; r < 4; ++r) {                                       \
            float y = acc[s][mt][nc][r] * sc + sh;                            \
            rv[r] += wk * y * fast_sigmoid(y);                                \
          }                                                                   \
        }                                                                     \
        float* ob = out + ((size_t)b * C_ + co) * HW_ +                       \
                    (size_t)((R0) + j) * W_ + c0 + m2 * 16 + sl * 4;          \
        *(f32x4*)ob = rv;                                                     \
      }

  // ---- pre-barrier: issue tile-0's first two halo rows (overlap DMA drain)
  bf16x8 FA[6], FB[6];
  const int r0t0 = rowg * 16 + wid * 2;     // tile-0 first image row
  const int r0t1 = r0t0 + 8;                // tile-1 first image row
  LOADROW(FA, r0t0, 0)
  LOADROW(FB, r0t0, 1)

  __syncthreads();                          // drains gload_lds + frag loads

  f32x4 acc[2][4][2];                       // [exp][mt=j*2+m2][nc]
#pragma unroll
  for (int s = 0; s < 2; ++s)
#pragma unroll
    for (int mt = 0; mt < 4; ++mt)
#pragma unroll
      for (int nc = 0; nc < 2; ++nc) acc[s][mt][nc] = (f32x4){0.f, 0.f, 0.f, 0.f};

  // ================= tile 0 =================
  MAINLOOP(r0t0, FA, FB)

  // prefetch tile-1 lead rows into fresh names; hidden under the epilogue
  bf16x8 NA[6], NB[6];
  LOADROW(NA, r0t1, 0)
  LOADROW(NB, r0t1, 1)

  EPILOGUE(r0t0)

  // ================= tile 1 =================
#pragma unroll
  for (int s = 0; s < 2; ++s)
#pragma unroll
    for (int mt = 0; mt < 4; ++mt)
#pragma unroll
      for (int nc = 0; nc < 2; ++nc) acc[s][mt][nc] = (f32x4){0.f, 0.f, 0.f, 0.f};

  MAINLOOP(r0t1, NA, NB)
  EPILOGUE(r0t1)

#undef LOADROW
#undef MAINLOOP
#undef EPILOGUE
}

// ---------------- fallback (R2 single kernel) if ws too small ----------------
#define FHALO 18
#define FNPX (FHALO * FHALO)
#define FPX_B 64
#define FIN_LDS_B (FNPX * FPX_B)
#define FSC_OFF (FIN_LDS_B + 2 * A_LDS_B)
#define FLDS_TOTAL (FSC_OFF + 2 * C_ * 8)
#define TH 16
#define TW 16

__global__ __launch_bounds__(256, 2)
void moe_fallback_kernel(const float* __restrict__ x,
                         const float* __restrict__ weights,
                         const int* __restrict__ indices,
                         const float* __restrict__ Wc,
                         const float* __restrict__ gamma,
                         const float* __restrict__ beta,
                         const float* __restrict__ mean,
                         const float* __restrict__ var,
                         float* __restrict__ out) {
  __shared__ __align__(16) unsigned char lds[FLDS_TOTAL];
  unsigned char* in_t = lds;
  unsigned char* aw0  = lds + FIN_LDS_B;
  unsigned char* aw1  = lds + FIN_LDS_B + A_LDS_B;
  float*         scsh = (float*)(lds + FSC_OFF);

  const int tid = threadIdx.x;
  const int tiles_per_row = W_ / TW;
  const int tiles_per_img = (H_ / TH) * tiles_per_row;
  const int b    = blockIdx.x / tiles_per_img;
  const int tile = blockIdx.x % tiles_per_img;
  const int th0  = (tile / tiles_per_row) * TH;
  const int tw0  = (tile % tiles_per_row) * TW;

  const int   e0  = indices[b * K_ + 0];
  const int   e1  = indices[b * K_ + 1];
  const float wk0 = weights[b * K_ + 0];
  const float wk1 = weights[b * K_ + 1];
  const bool  dup = (e0 == e1);
  const float wka = dup ? (wk0 + wk1) : wk0;

  const float* xb = x + (size_t)b * C_ * HW_;
  for (int i = tid; i < FNPX * 4; i += 256) {
    int px = i % FNPX;
    int cb = i / FNPX;
    int hy = px / FHALO, hx = px % FHALO;
    int gh = th0 + hy - 1, gw = tw0 + hx - 1;
    u16x8 pk = (u16x8)0;
    if (gh >= 0 && gh < H_ && gw >= 0 && gw < W_) {
      const float* src = xb + (size_t)(cb * 8) * HW_ + (size_t)gh * W_ + gw;
#pragma unroll
      for (int j = 0; j < 8; ++j) pk[j] = f2bf(src[(size_t)j * HW_]);
    }
    int slot = cb ^ (px & 3);
    *(u16x8*)(in_t + px * FPX_B + slot * 16) = pk;
  }
  {
    int co  = tid >> 3;
    int ci4 = (tid & 7) * 4;
#pragma unroll
    for (int s = 0; s < 2; ++s) {
      int e = s ? e1 : e0;
      const float* wp = Wc + (size_t)e * C_ * C_ * 9 + (size_t)co * C_ * 9 + (size_t)ci4 * 9;
      float wv[36];
#pragma unroll
      for (int j = 0; j < 36; ++j) wv[j] = wp[j];
      unsigned char* arow = (s ? aw1 : aw0) + co * AROW_B + ci4 * 2;
#pragma unroll
      for (int o = 0; o < 9; ++o) {
        u16x4 pk;
#pragma unroll
        for (int q = 0; q < 4; ++q) pk[q] = f2bf(wv[q * 9 + o]);
        *(u16x4*)(arow + o * 64) = pk;
      }
    }
  }
  if (tid < 64) {
    int s  = tid >> 5;
    int co = tid & 31;
    int e  = s ? e1 : e0;
    float g  = gamma[e * C_ + co];
    float bt = beta[e * C_ + co];
    float mn = mean[e * C_ + co];
    float vr = var[e * C_ + co];
    float sc = g * rsqrtf(vr + EPS_);
    scsh[(s * C_ + co) * 2 + 0] = sc;
    scsh[(s * C_ + co) * 2 + 1] = bt - mn * sc;
  }
  __syncthreads();

  const int lane = tid & 63;
  const int w    = tid >> 6;
  const int lx   = lane & 15;
  const int sl   = lane >> 4;

  f32x4 acc[2][2][4];
#pragma unroll
  for (int s = 0; s < 2; ++s)
#pragma unroll
    for (int m = 0; m < 2; ++m)
#pragma unroll
      for (int j = 0; j < 4; ++j) acc[s][m][j] = (f32x4){0.f, 0.f, 0.f, 0.f};

  int dy = 0, dx = 0;
#pragma unroll 1
  for (int o = 0; o < 9; ++o) {
    bf16x8 bf[4];
#pragma unroll
    for (int j = 0; j < 4; ++j) {
      int hp   = (4 * w + j + dy) * FHALO + (lx + dx);
      int slot = sl ^ (hp & 3);
      bf[j] = *(const bf16x8*)(in_t + hp * FPX_B + slot * 16);
    }
    bf16x8 af0[2], af1[2];
#pragma unroll
    for (int m = 0; m < 2; ++m) {
      int ro = (m * 16 + lx) * AROW_B + o * 64 + sl * 16;
      af0[m] = *(const bf16x8*)(aw0 + ro);
      af1[m] = *(const bf16x8*)(aw1 + ro);
    }
#pragma unroll
    for (int m = 0; m < 2; ++m)
#pragma unroll
      for (int j = 0; j < 4; ++j)
        acc[0][m][j] = __builtin_amdgcn_mfma_f32_16x16x32_bf16(af0[m], bf[j], acc[0][m][j], 0, 0, 0);
    if (!dup) {
#pragma unroll
      for (int m = 0; m < 2; ++m)
#pragma unroll
        for (int j = 0; j < 4; ++j)
          acc[1][m][j] = __builtin_amdgcn_mfma_f32_16x16x32_bf16(af1[m], bf[j], acc[1][m][j], 0, 0, 0);
    }
    if (++dx == 3) { dx = 0; ++dy; }
  }

  float res[2][4][4];
#pragma unroll
  for (int m = 0; m < 2; ++m)
#pragma unroll
    for (int j = 0; j < 4; ++j)
#pragma unroll
      for (int r = 0; r < 4; ++r) res[m][j][r] = 0.f;

#pragma unroll
  for (int s = 0; s < 2; ++s) {
    if (s == 1 && dup) break;
    float wk = s ? wk1 : wka;
#pragma unroll
    for (int m = 0; m < 2; ++m)
#pragma unroll
      for (int r = 0; r < 4; ++r) {
        int co = m * 16 + sl * 4 + r;
        float sc = scsh[(s * C_ + co) * 2 + 0];
        float sh = scsh[(s * C_ + co) * 2 + 1];
#pragma unroll
        for (int j = 0; j < 4; ++j) {
          float y = acc[s][m][j][r] * sc + sh;
          res[m][j][r] += wk * y * fast_sigmoid(y);
        }
      }
  }
#pragma unroll
  for (int m = 0; m < 2; ++m)
#pragma unroll
    for (int r = 0; r < 4; ++r) {
      int co = m * 16 + sl * 4 + r;
      float* ob = out + ((size_t)b * C_ + co) * HW_ + (size_t)th0 * W_ + tw0 + lx;
#pragma unroll
      for (int j = 0; j < 4; ++j)
        ob[(size_t)(4 * w + j) * W_] = res[m][j][r];
    }
}

extern "C" void kernel_launch(void* const* d_in, const int* in_sizes, int n_in,
                              void* d_out, int out_size, void* d_ws, size_t ws_size,
                              hipStream_t stream) {
  const float* x       = (const float*)d_in[0];
  const float* weights = (const float*)d_in[1];
  const int*   indices = (const int*)d_in[2];
  const float* Wc      = (const float*)d_in[3];
  const float* gamma   = (const float*)d_in[4];
  const float* beta    = (const float*)d_in[5];
  const float* mean    = (const float*)d_in[6];
  const float* var     = (const float*)d_in[7];
  float* out = (float*)d_out;

  if (d_ws != nullptr && ws_size >= WS_NEEDED) {
    unsigned short* wsu = (unsigned short*)d_ws;
    const unsigned short* aw_all   = (const unsigned short*)((char*)d_ws + AW_OFF);
    const float*          scsh_all = (const float*)((char*)d_ws + SCSH_OFF);
    prep_kernel<<<B_ * HP_ + E_, 256, 0, stream>>>(x, Wc, gamma, beta, mean, var, wsu);
    conv_kernel<<<2048, 256, 0, stream>>>(wsu, aw_all, scsh_all, weights, indices, out);
  } else {
    moe_fallback_kernel<<<B_ * 64, 256, 0, stream>>>(
        x, weights, indices, Wc, gamma, beta, mean, var, out);
  }
}

// Round 13
// 89.564 us; speedup vs baseline: 1.1110x; 1.0698x over previous
//
#include <hip/hip_runtime.h>
#include <math.h>

// MoE conv container, two-phase (R10 configuration == best measured, 89.9us):
//  prep: x NCHW fp32 -> zero-padded NHWC bf16 (130x130x32) in ws (XCD-swizzled
//        writes matching conv's read affinity), + weights -> MFMA A-layout bf16
//        + BN scale/shift tables.  (~28us ~= BW floor)
//  conv: one 16x32-px region per block = 2 fully-unrolled 8x32 tiles (A panels
//        staged once). 4 waves x [2 rows x 32 cols] per tile. Pixel frags
//        direct from NHWC-padded global (16B/lane, L2/L3-local). Swapped MFMA
//        operands -> dwordx4 stores filling full 128B lines.
//        Latency hiding: tile-0 frag loads issued BEFORE the staging barrier;
//        tile-1 lead rows (fresh names NA/NB) issued after tile-0's last MFMA
//        and hidden under tile-0's epilogue; epilogue STREAMS stores per quad
//        (res liveness 32->4 regs).
//  Lessons encoded: R8 = carrying frags across epilogue in a rolled loop =>
//  scratch spill. R11 = LDS store-transpose of stores = -10us (stores already
//  merge in L2; R6 verified WRITE == ideal). R12 = whole-kernel BN register
//  caching = -6us (adds peak liveness at the MAINLOOP+prefetch pinch point;
//  LDS scsh reads in the epilogue are NOT on the critical path).
// Fallback to single-kernel (R2) path if ws too small.

#define B_ 64
#define C_ 32
#define H_ 128
#define W_ 128
#define E_ 4
#define K_ 2
#define EPS_ 1e-5f
#define HW_ (H_ * W_)
#define HP_ 130
#define WP_ 130

#define AROW_B 592                          // 288 bf16 = 576B + 16B pad (odd 16B stride)
#define A_LDS_B (C_ * AROW_B)               // 18944 per expert
#define XPAD_BYTES ((size_t)B_ * HP_ * WP_ * C_ * 2)   // 69,222,400
#define AW_OFF   XPAD_BYTES
#define AW_BYTES ((size_t)E_ * A_LDS_B)     // 75,776
#define SCSH_OFF (AW_OFF + AW_BYTES)
#define WS_NEEDED (SCSH_OFF + (size_t)E_ * C_ * 2 * 4)

// conv LDS layout: A panels + scale/shift only
#define LDS_AW   0
#define LDS_SCSH (2 * A_LDS_B)             // 37888
#define LDS_TOT  (LDS_SCSH + 512)          // 38400

typedef __attribute__((ext_vector_type(4))) float  f32x4;
typedef __attribute__((ext_vector_type(8))) short  bf16x8;
typedef __attribute__((ext_vector_type(8))) unsigned short u16x8;
typedef __attribute__((ext_vector_type(4))) unsigned short u16x4;

__device__ inline unsigned short f2bf(float f) {  // round-to-nearest-even
  unsigned u = __builtin_bit_cast(unsigned, f);
  return (unsigned short)((u + 0x7fffu + ((u >> 16) & 1u)) >> 16);
}

__device__ inline float fast_sigmoid(float y) {   // hw rcp: 1 op vs ~9-op div
  return __builtin_amdgcn_rcpf(1.f + __expf(-y));
}

__device__ inline void gload16(const void* g, const void* l) {
  __builtin_amdgcn_global_load_lds(
      (const __attribute__((address_space(1))) unsigned int*)g,
      (__attribute__((address_space(3))) unsigned int*)l, 16, 0, 0);
}

// ---------------- phase A: transpose/convert + weight prep ----------------
__global__ __launch_bounds__(256, 4)
void prep_kernel(const float* __restrict__ x,
                 const float* __restrict__ Wc,
                 const float* __restrict__ gamma,
                 const float* __restrict__ beta,
                 const float* __restrict__ mean,
                 const float* __restrict__ var,
                 unsigned short* __restrict__ wsu) {
  const int bid = blockIdx.x;
  const int tid = threadIdx.x;

  if (bid >= B_ * HP_) {
    // ---- weight block: expert e -> A[e][co][o*32+ci] bf16, stride 592B ----
    int e = bid - B_ * HP_;
    unsigned short* aw = (unsigned short*)((char*)wsu + AW_OFF) + (size_t)e * (A_LDS_B / 2);
    int co  = tid >> 3;
    int ci4 = (tid & 7) * 4;
    const float* wp = Wc + (((size_t)e * C_ + co) * C_ + ci4) * 9;
    float wv[36];
#pragma unroll
    for (int j = 0; j < 36; ++j) wv[j] = wp[j];
    unsigned short* arow = aw + co * (AROW_B / 2) + ci4;
#pragma unroll
    for (int o = 0; o < 9; ++o) {
      u16x4 pk;
#pragma unroll
      for (int q = 0; q < 4; ++q) pk[q] = f2bf(wv[q * 9 + o]);
      *(u16x4*)(arow + o * C_) = pk;
    }
    if (tid < C_) {
      float g  = gamma[e * C_ + tid];
      float bt = beta[e * C_ + tid];
      float mn = mean[e * C_ + tid];
      float vr = var[e * C_ + tid];
      float sc = g * rsqrtf(vr + EPS_);
      float* scsh = (float*)((char*)wsu + SCSH_OFF);
      scsh[(e * C_ + tid) * 2 + 0] = sc;
      scsh[(e * C_ + tid) * 2 + 1] = bt - mn * sc;
    }
    return;
  }

  // XCD-aligned bijection: sample b handled by blocks with bid%8 == b%8,
  // matching conv_kernel's read affinity (per-XCD L2 locality).
  const int xg = bid >> 3;                  // 0..1039
  const int u  = bid & 7;
  const int b  = (xg / HP_) * 8 + u;        // 0..63
  const int hp = xg % HP_;                  // 0..129
  unsigned short* xrow = wsu + ((size_t)b * HP_ + hp) * WP_ * C_;

  if (hp == 0 || hp == HP_ - 1) {           // zero pad rows
    u16x8 z = (u16x8)0;
    for (int c = tid; c < WP_ * C_ / 8; c += 256) *(u16x8*)(xrow + c * 8) = z;
    return;
  }

  __shared__ float tile[C_ * W_];           // 16 KB
  const int h = hp - 1;
#pragma unroll
  for (int p = 0; p < 4; ++p) {
    int n  = p * 1024 + tid * 4;
    int c  = n >> 7;
    int px = n & 127;
    *(f32x4*)(tile + n) =
        *(const f32x4*)(x + (((size_t)b * C_ + c) * H_ + h) * W_ + px);
  }
  __syncthreads();

  const int px = tid >> 1;
  const int c0 = (tid & 1) * 16;
  u16x8 o0, o1;
#pragma unroll
  for (int j = 0; j < 8; ++j) o0[j] = f2bf(tile[(c0 + j) * W_ + px]);
#pragma unroll
  for (int j = 0; j < 8; ++j) o1[j] = f2bf(tile[(c0 + 8 + j) * W_ + px]);
  unsigned short* dst = xrow + (px + 1) * C_ + c0;
  *(u16x8*)dst = o0;
  *(u16x8*)(dst + 8) = o1;

  if (tid < 4) {                            // zero pad cols 0 and 129
    int pxb = (tid >> 1) ? (WP_ - 1) : 0;
    int hf  = tid & 1;
    u16x8 z = (u16x8)0;
    unsigned short* d2 = xrow + pxb * C_ + hf * 16;
    *(u16x8*)d2 = z;
    *(u16x8*)(d2 + 8) = z;
  }
}

// ---------------- phase B: conv via MFMA (swapped operands) ----------------
__global__ __launch_bounds__(256, 3)
void conv_kernel(const unsigned short* __restrict__ xpad,
                 const unsigned short* __restrict__ aw_all,
                 const float* __restrict__ scsh_all,
                 const float* __restrict__ weights,
                 const int* __restrict__ indices,
                 float* __restrict__ out) {
  __shared__ __align__(16) unsigned char lds[LDS_TOT];
  const int tid  = threadIdx.x;
  const int lane = tid & 63;
  const int wid  = tid >> 6;

  // XCD swizzle: all 32 blocks of a sample land on one XCD (bid%8 assumption).
  const int bid  = blockIdx.x;              // grid 2048
  const int xcd  = bid & 7;
  const int ii   = bid >> 3;                // 0..255
  const int b    = (ii >> 5) * 8 + xcd;     // bijective over (b, region)
  const int reg_ = ii & 31;
  const int rowg = reg_ >> 2;               // 0..7 -> 16-row band
  const int cseg = reg_ & 3;                // 0..3 -> 32-col segment
  const int c0   = cseg * 32;

  const int   e0  = indices[b * K_ + 0];
  const int   e1  = indices[b * K_ + 1];
  const float wk0 = weights[b * K_ + 0];
  const float wk1 = weights[b * K_ + 1];
  const bool  dup = (e0 == e1);
  const float wka = dup ? (wk0 + wk1) : wk0;

  // ---- stage A panels (1 or 2 experts) via global_load_lds ----
  {
    const int nA = (dup ? 1 : 2) * 1184;    // 16B chunks
    for (int base = wid * 64; base < nA; base += 256) {
      int c = base + lane;
      int e = (c < 1184) ? e0 : e1;
      int r = (c < 1184) ? c : c - 1184;
      const unsigned short* src = aw_all + (size_t)e * (A_LDS_B / 2) + r * 8;
      if (c < nA) gload16(src, lds + LDS_AW + base * 16);
    }
  }
  // ---- stage BN scale/shift ----
  if (tid < 2 * C_) {
    int s  = tid >> 5;
    int co = tid & 31;
    int e  = s ? e1 : e0;
    float* d = (float*)(lds + LDS_SCSH) + (s * C_ + co) * 2;
    d[0] = scsh_all[(e * C_ + co) * 2 + 0];
    d[1] = scsh_all[(e * C_ + co) * 2 + 1];
  }

  const int lx = lane & 15;                 // px within M-tile / co within N-tile
  const int sl = lane >> 4;                 // k-slot (8 ci)

  // Column-base pointer for this wave's 32-col segment (row added per tile).
  const unsigned short* cbase =
      xpad + ((size_t)b * HP_ * WP_ + c0 + lx) * C_ + sl * 8;

  // window s = m2*3+dx -> col offset (s/3)*16 + (s%3); row hr in padded coords.
#define LOADROW(dst, rbase, hr)                                               \
  {                                                                           \
    const unsigned short* _p = cbase + ((size_t)((rbase) + (hr)) * WP_) * C_; \
    _Pragma("unroll")                                                         \
    for (int s_ = 0; s_ < 6; ++s_)                                            \
      dst[s_] = *(const bf16x8*)(_p + ((s_ / 3) * 16 + (s_ % 3)) * C_);       \
  }

  // 9-tap MFMA main loop over rolling rows A0/B0 (consumed; end: rows 2,3).
#define MAINLOOP(R0, A0, B0)                                                  \
  _Pragma("unroll")                                                           \
  for (int dy = 0; dy < 3; ++dy) {                                            \
    bf16x8 FC[6];                                                             \
    if (dy < 2) LOADROW(FC, R0, dy + 2)                                       \
    _Pragma("unroll")                                                         \
    for (int dx = 0; dx < 3; ++dx) {                                          \
      const int o = dy * 3 + dx;                                              \
      bf16x8 bf0[2], bf1[2];                                                  \
      _Pragma("unroll")                                                       \
      for (int nc = 0; nc < 2; ++nc)                                          \
        bf0[nc] = *(const bf16x8*)(lds + LDS_AW + (nc * 16 + lx) * AROW_B + o * 64 + sl * 16); \
      if (!dup) {                                                             \
        _Pragma("unroll")                                                     \
        for (int nc = 0; nc < 2; ++nc)                                        \
          bf1[nc] = *(const bf16x8*)(lds + LDS_AW + A_LDS_B + (nc * 16 + lx) * AROW_B + o * 64 + sl * 16); \
      }                                                                       \
      __builtin_amdgcn_s_setprio(1);                                          \
      _Pragma("unroll")                                                       \
      for (int j = 0; j < 2; ++j)                                             \
        _Pragma("unroll")                                                     \
        for (int m2 = 0; m2 < 2; ++m2) {                                      \
          bf16x8 Af = j ? B0[m2 * 3 + dx] : A0[m2 * 3 + dx];                  \
          _Pragma("unroll")                                                   \
          for (int nc = 0; nc < 2; ++nc)                                      \
            acc[0][j * 2 + m2][nc] =                                          \
                __builtin_amdgcn_mfma_f32_16x16x32_bf16(Af, bf0[nc], acc[0][j * 2 + m2][nc], 0, 0, 0); \
          if (!dup) {                                                         \
            _Pragma("unroll")                                                 \
            for (int nc = 0; nc < 2; ++nc)                                    \
              acc[1][j * 2 + m2][nc] =                                        \
                  __builtin_amdgcn_mfma_f32_16x16x32_bf16(Af, bf1[nc], acc[1][j * 2 + m2][nc], 0, 0, 0); \
          }                                                                   \
        }                                                                     \
      __builtin_amdgcn_s_setprio(0);                                          \
    }                                                                         \
    _Pragma("unroll")                                                         \
    for (int s_ = 0; s_ < 6; ++s_) { A0[s_] = B0[s_]; B0[s_] = FC[s_]; }      \
  }

  // Streamed epilogue: compute one f32x4 quad (both experts) and store it
  // immediately -> res liveness is 4 regs, not 32.
#define EPILOGUE(R0)                                                          \
  _Pragma("unroll")                                                           \
  for (int j = 0; j < 2; ++j)                                                 \
    _Pragma("unroll")                                                         \
    for (int m2 = 0; m2 < 2; ++m2)                                            \
      _Pragma("unroll")                                                       \
      for (int nc = 0; nc < 2; ++nc) {                                        \
        const int mt = j * 2 + m2;                                            \
        const int co = nc * 16 + lx;                                          \
        f32x4 rv = (f32x4){0.f, 0.f, 0.f, 0.f};                               \
        _Pragma("unroll")                                                     \
        for (int s = 0; s < 2; ++s) {                                         \
          if (s == 1 && dup) break;                                           \
          float wk = s ? wk1 : wka;                                           \
          float sc = scshl[(s * C_ + co) * 2 + 0];                            \
          float sh = scshl[(s * C_ + co) * 2 + 1];                            \
          _Pragma("unroll")                                                   \
          for (int r = 0; r < 4; ++r) {                                       \
            float y = acc[s][mt][nc][r] * sc + sh;                            \
            rv[r] += wk * y * fast_sigmoid(y);                                \
          }                                                                   \
        }                                                                     \
        float* ob = out + ((size_t)b * C_ + co) * HW_ +                       \
                    (size_t)((R0) + j) * W_ + c0 + m2 * 16 + sl * 4;          \
        *(f32x4*)ob = rv;                                                     \
      }

  // ---- pre-barrier: issue tile-0's first two halo rows (overlap DMA drain)
  bf16x8 FA[6], FB[6];
  const int r0t0 = rowg * 16 + wid * 2;     // tile-0 first image row
  const int r0t1 = r0t0 + 8;                // tile-1 first image row
  LOADROW(FA, r0t0, 0)
  LOADROW(FB, r0t0, 1)

  __syncthreads();                          // drains gload_lds + frag loads

  const float* scshl = (const float*)(lds + LDS_SCSH);

  f32x4 acc[2][4][2];                       // [exp][mt=j*2+m2][nc]
#pragma unroll
  for (int s = 0; s < 2; ++s)
#pragma unroll
    for (int mt = 0; mt < 4; ++mt)
#pragma unroll
      for (int nc = 0; nc < 2; ++nc) acc[s][mt][nc] = (f32x4){0.f, 0.f, 0.f, 0.f};

  // ================= tile 0 =================
  MAINLOOP(r0t0, FA, FB)

  // prefetch tile-1 lead rows into fresh names; hidden under the epilogue
  bf16x8 NA[6], NB[6];
  LOADROW(NA, r0t1, 0)
  LOADROW(NB, r0t1, 1)

  EPILOGUE(r0t0)

  // ================= tile 1 =================
#pragma unroll
  for (int s = 0; s < 2; ++s)
#pragma unroll
    for (int mt = 0; mt < 4; ++mt)
#pragma unroll
      for (int nc = 0; nc < 2; ++nc) acc[s][mt][nc] = (f32x4){0.f, 0.f, 0.f, 0.f};

  MAINLOOP(r0t1, NA, NB)
  EPILOGUE(r0t1)

#undef LOADROW
#undef MAINLOOP
#undef EPILOGUE
}

// ---------------- fallback (R2 single kernel) if ws too small ----------------
#define FHALO 18
#define FNPX (FHALO * FHALO)
#define FPX_B 64
#define FIN_LDS_B (FNPX * FPX_B)
#define FSC_OFF (FIN_LDS_B + 2 * A_LDS_B)
#define FLDS_TOTAL (FSC_OFF + 2 * C_ * 8)
#define TH 16
#define TW 16

__global__ __launch_bounds__(256, 2)
void moe_fallback_kernel(const float* __restrict__ x,
                         const float* __restrict__ weights,
                         const int* __restrict__ indices,
                         const float* __restrict__ Wc,
                         const float* __restrict__ gamma,
                         const float* __restrict__ beta,
                         const float* __restrict__ mean,
                         const float* __restrict__ var,
                         float* __restrict__ out) {
  __shared__ __align__(16) unsigned char lds[FLDS_TOTAL];
  unsigned char* in_t = lds;
  unsigned char* aw0  = lds + FIN_LDS_B;
  unsigned char* aw1  = lds + FIN_LDS_B + A_LDS_B;
  float*         scsh = (float*)(lds + FSC_OFF);

  const int tid = threadIdx.x;
  const int tiles_per_row = W_ / TW;
  const int tiles_per_img = (H_ / TH) * tiles_per_row;
  const int b    = blockIdx.x / tiles_per_img;
  const int tile = blockIdx.x % tiles_per_img;
  const int th0  = (tile / tiles_per_row) * TH;
  const int tw0  = (tile % tiles_per_row) * TW;

  const int   e0  = indices[b * K_ + 0];
  const int   e1  = indices[b * K_ + 1];
  const float wk0 = weights[b * K_ + 0];
  const float wk1 = weights[b * K_ + 1];
  const bool  dup = (e0 == e1);
  const float wka = dup ? (wk0 + wk1) : wk0;

  const float* xb = x + (size_t)b * C_ * HW_;
  for (int i = tid; i < FNPX * 4; i += 256) {
    int px = i % FNPX;
    int cb = i / FNPX;
    int hy = px / FHALO, hx = px % FHALO;
    int gh = th0 + hy - 1, gw = tw0 + hx - 1;
    u16x8 pk = (u16x8)0;
    if (gh >= 0 && gh < H_ && gw >= 0 && gw < W_) {
      const float* src = xb + (size_t)(cb * 8) * HW_ + (size_t)gh * W_ + gw;
#pragma unroll
      for (int j = 0; j < 8; ++j) pk[j] = f2bf(src[(size_t)j * HW_]);
    }
    int slot = cb ^ (px & 3);
    *(u16x8*)(in_t + px * FPX_B + slot * 16) = pk;
  }
  {
    int co  = tid >> 3;
    int ci4 = (tid & 7) * 4;
#pragma unroll
    for (int s = 0; s < 2; ++s) {
      int e = s ? e1 : e0;
      const float* wp = Wc + (size_t)e * C_ * C_ * 9 + (size_t)co * C_ * 9 + (size_t)ci4 * 9;
      float wv[36];
#pragma unroll
      for (int j = 0; j < 36; ++j) wv[j] = wp[j];
      unsigned char* arow = (s ? aw1 : aw0) + co * AROW_B + ci4 * 2;
#pragma unroll
      for (int o = 0; o < 9; ++o) {
        u16x4 pk;
#pragma unroll
        for (int q = 0; q < 4; ++q) pk[q] = f2bf(wv[q * 9 + o]);
        *(u16x4*)(arow + o * 64) = pk;
      }
    }
  }
  if (tid < 64) {
    int s  = tid >> 5;
    int co = tid & 31;
    int e  = s ? e1 : e0;
    float g  = gamma[e * C_ + co];
    float bt = beta[e * C_ + co];
    float mn = mean[e * C_ + co];
    float vr = var[e * C_ + co];
    float sc = g * rsqrtf(vr + EPS_);
    scsh[(s * C_ + co) * 2 + 0] = sc;
    scsh[(s * C_ + co) * 2 + 1] = bt - mn * sc;
  }
  __syncthreads();

  const int lane = tid & 63;
  const int w    = tid >> 6;
  const int lx   = lane & 15;
  const int sl   = lane >> 4;

  f32x4 acc[2][2][4];
#pragma unroll
  for (int s = 0; s < 2; ++s)
#pragma unroll
    for (int m = 0; m < 2; ++m)
#pragma unroll
      for (int j = 0; j < 4; ++j) acc[s][m][j] = (f32x4){0.f, 0.f, 0.f, 0.f};

  int dy = 0, dx = 0;
#pragma unroll 1
  for (int o = 0; o < 9; ++o) {
    bf16x8 bf[4];
#pragma unroll
    for (int j = 0; j < 4; ++j) {
      int hp   = (4 * w + j + dy) * FHALO + (lx + dx);
      int slot = sl ^ (hp & 3);
      bf[j] = *(const bf16x8*)(in_t + hp * FPX_B + slot * 16);
    }
    bf16x8 af0[2], af1[2];
#pragma unroll
    for (int m = 0; m < 2; ++m) {
      int ro = (m * 16 + lx) * AROW_B + o * 64 + sl * 16;
      af0[m] = *(const bf16x8*)(aw0 + ro);
      af1[m] = *(const bf16x8*)(aw1 + ro);
    }
#pragma unroll
    for (int m = 0; m < 2; ++m)
#pragma unroll
      for (int j = 0; j < 4; ++j)
        acc[0][m][j] = __builtin_amdgcn_mfma_f32_16x16x32_bf16(af0[m], bf[j], acc[0][m][j], 0, 0, 0);
    if (!dup) {
#pragma unroll
      for (int m = 0; m < 2; ++m)
#pragma unroll
        for (int j = 0; j < 4; ++j)
          acc[1][m][j] = __builtin_amdgcn_mfma_f32_16x16x32_bf16(af1[m], bf[j], acc[1][m][j], 0, 0, 0);
    }
    if (++dx == 3) { dx = 0; ++dy; }
  }

  float res[2][4][4];
#pragma unroll
  for (int m = 0; m < 2; ++m)
#pragma unroll
    for (int j = 0; j < 4; ++j)
#pragma unroll
      for (int r = 0; r < 4; ++r) res[m][j][r] = 0.f;

#pragma unroll
  for (int s = 0; s < 2; ++s) {
    if (s == 1 && dup) break;
    float wk = s ? wk1 : wka;
#pragma unroll
    for (int m = 0; m < 2; ++m)
#pragma unroll
      for (int r = 0; r < 4; ++r) {
        int co = m * 16 + sl * 4 + r;
        float sc = scsh[(s * C_ + co) * 2 + 0];
        float sh = scsh[(s * C_ + co) * 2 + 1];
#pragma unroll
        for (int j = 0; j < 4; ++j) {
          float y = acc[s][m][j][r] * sc + sh;
          res[m][j][r] += wk * y * fast_sigmoid(y);
        }
      }
  }
#pragma unroll
  for (int m = 0; m < 2; ++m)
#pragma unroll
    for (int r = 0; r < 4; ++r) {
      int co = m * 16 + sl * 4 + r;
      float* ob = out + ((size_t)b * C_ + co) * HW_ + (size_t)th0 * W_ + tw0 + lx;
#pragma unroll
      for (int j = 0; j < 4; ++j)
        ob[(size_t)(4 * w + j) * W_] = res[m][j][r];
    }
}

extern "C" void kernel_launch(void* const* d_in, const int* in_sizes, int n_in,
                              void* d_out, int out_size, void* d_ws, size_t ws_size,
                              hipStream_t stream) {
  const float* x       = (const float*)d_in[0];
  const float* weights = (const float*)d_in[1];
  const int*   indices = (const int*)d_in[2];
  const float* Wc      = (const float*)d_in[3];
  const float* gamma   = (const float*)d_in[4];
  const float* beta    = (const float*)d_in[5];
  const float* mean    = (const float*)d_in[6];
  const float* var     = (const float*)d_in[7];
  float* out = (float*)d_out;

  if (d_ws != nullptr && ws_size >= WS_NEEDED) {
    unsigned short* wsu = (unsigned short*)d_ws;
    const unsigned short* aw_all   = (const unsigned short*)((char*)d_ws + AW_OFF);
    const float*          scsh_all = (const float*)((char*)d_ws + SCSH_OFF);
    prep_kernel<<<B_ * HP_ + E_, 256, 0, stream>>>(x, Wc, gamma, beta, mean, var, wsu);
    conv_kernel<<<2048, 256, 0, stream>>>(wsu, aw_all, scsh_all, weights, indices, out);
  } else {
    moe_fallback_kernel<<<B_ * 64, 256, 0, stream>>>(
        x, weights, indices, Wc, gamma, beta, mean, var, out);
  }
}